// Round 1
// baseline (629.647 us; speedup 1.0000x reference)
//
#include <hip/hip_runtime.h>
#include <hip/hip_bf16.h>
#include <math.h>

// MultiSimilarityLoss: B=8192, D=128. fp32 baseline (no fp32 MFMA on CDNA4).
// Two tiled sim passes: stage1 (row min_pos/max_neg), stage2 (masked exp sums).

#define TI 64
#define TJ 64
#define DDIM 128
#define LDW 132            // LDS row stride (floats): 528B = 16B-aligned, bank skew 4
#define THREADS 256
#define SPLITS 4

static constexpr float F_THRESH = 0.5f;
static constexpr float F_MARGIN = 0.1f;
static constexpr float F_SPOS   = 2.0f;
static constexpr float F_SNEG   = 40.0f;
static constexpr float F_EPS    = 1e-5f;

// ---------------------------------------------------------------- stage 1
__global__ __launch_bounds__(THREADS, 2)
void ms_stage1(const float* __restrict__ feats, const int* __restrict__ labels,
               float* __restrict__ minp_part, float* __restrict__ maxn_part, int B)
{
    __shared__ float As[TI * LDW];
    __shared__ float Bs[TJ * LDW];
    __shared__ int   Alab[TI];
    __shared__ int   Blab[TJ];

    const int tid = threadIdx.x;
    const int i0  = blockIdx.x * TI;
    const int jchunk = B / SPLITS;
    const int j0  = blockIdx.y * jchunk;

    // A tile: coalesced float4 reads, conflict-free b128 LDS writes
    for (int v = tid; v < TI * (DDIM / 4); v += THREADS) {
        int r  = v >> 5;            // 32 float4 per row
        int k4 = (v & 31) << 2;
        *(float4*)&As[r * LDW + k4] =
            *(const float4*)&feats[(size_t)(i0 + r) * DDIM + k4];
    }
    if (tid < TI) Alab[tid] = labels[i0 + tid];

    const int tx = tid & 15;        // cols tx + 16j
    const int ty = tid >> 4;        // rows 4ty + i

    float minp[4] = { INFINITY,  INFINITY,  INFINITY,  INFINITY};
    float maxn[4] = {-INFINITY, -INFINITY, -INFINITY, -INFINITY};

    const float* ap = &As[(ty * 4) * LDW];
    const float* bp = &Bs[tx * LDW];

    for (int jt = 0; jt < jchunk; jt += TJ) {
        __syncthreads();            // guard Bs reuse
        for (int v = tid; v < TJ * (DDIM / 4); v += THREADS) {
            int c  = v >> 5;
            int k4 = (v & 31) << 2;
            *(float4*)&Bs[c * LDW + k4] =
                *(const float4*)&feats[(size_t)(j0 + jt + c) * DDIM + k4];
        }
        if (tid < TJ) Blab[tid] = labels[j0 + jt + tid];
        __syncthreads();

        float acc[4][4];
        #pragma unroll
        for (int i = 0; i < 4; ++i)
            #pragma unroll
            for (int j = 0; j < 4; ++j) acc[i][j] = 0.f;

        #pragma unroll 4
        for (int k = 0; k < DDIM; k += 4) {
            float4 a[4], b[4];
            #pragma unroll
            for (int i = 0; i < 4; ++i) a[i] = *(const float4*)&ap[i * LDW + k];
            #pragma unroll
            for (int j = 0; j < 4; ++j) b[j] = *(const float4*)&bp[(j * 16) * LDW + k];
            #pragma unroll
            for (int i = 0; i < 4; ++i)
                #pragma unroll
                for (int j = 0; j < 4; ++j) {
                    acc[i][j] = fmaf(a[i].x, b[j].x, acc[i][j]);
                    acc[i][j] = fmaf(a[i].y, b[j].y, acc[i][j]);
                    acc[i][j] = fmaf(a[i].z, b[j].z, acc[i][j]);
                    acc[i][j] = fmaf(a[i].w, b[j].w, acc[i][j]);
                }
        }

        #pragma unroll
        for (int i = 0; i < 4; ++i) {
            int la = Alab[ty * 4 + i];
            #pragma unroll
            for (int j = 0; j < 4; ++j) {
                int lb  = Blab[tx + j * 16];
                float s = acc[i][j];
                if (la == lb) {
                    if (s < 1.0f - F_EPS) minp[i] = fminf(minp[i], s);
                } else {
                    maxn[i] = fmaxf(maxn[i], s);
                }
            }
        }
    }

    #pragma unroll
    for (int off = 1; off < 16; off <<= 1) {
        #pragma unroll
        for (int i = 0; i < 4; ++i) {
            minp[i] = fminf(minp[i], __shfl_xor(minp[i], off, 64));
            maxn[i] = fmaxf(maxn[i], __shfl_xor(maxn[i], off, 64));
        }
    }
    if (tx == 0) {
        #pragma unroll
        for (int i = 0; i < 4; ++i) {
            int row = i0 + ty * 4 + i;
            minp_part[(size_t)blockIdx.y * B + row] = minp[i];
            maxn_part[(size_t)blockIdx.y * B + row] = maxn[i];
        }
    }
}

// ---------------------------------------------------------------- combine
__global__ void ms_combine(const float* __restrict__ minp_part,
                           const float* __restrict__ maxn_part,
                           float* __restrict__ minp, float* __restrict__ maxn, int B)
{
    int i = blockIdx.x * blockDim.x + threadIdx.x;
    if (i >= B) return;
    float mn =  INFINITY, mx = -INFINITY;
    #pragma unroll
    for (int s = 0; s < SPLITS; ++s) {
        mn = fminf(mn, minp_part[(size_t)s * B + i]);
        mx = fmaxf(mx, maxn_part[(size_t)s * B + i]);
    }
    minp[i] = mn;
    maxn[i] = mx;
}

// ---------------------------------------------------------------- stage 2
__global__ __launch_bounds__(THREADS, 2)
void ms_stage2(const float* __restrict__ feats, const int* __restrict__ labels,
               const float* __restrict__ minp, const float* __restrict__ maxn,
               float* __restrict__ psum_part, float* __restrict__ nsum_part, int B)
{
    __shared__ float As[TI * LDW];
    __shared__ float Bs[TJ * LDW];
    __shared__ int   Alab[TI];
    __shared__ int   Blab[TJ];

    const int tid = threadIdx.x;
    const int i0  = blockIdx.x * TI;
    const int jchunk = B / SPLITS;
    const int j0  = blockIdx.y * jchunk;

    for (int v = tid; v < TI * (DDIM / 4); v += THREADS) {
        int r  = v >> 5;
        int k4 = (v & 31) << 2;
        *(float4*)&As[r * LDW + k4] =
            *(const float4*)&feats[(size_t)(i0 + r) * DDIM + k4];
    }
    if (tid < TI) Alab[tid] = labels[i0 + tid];

    const int tx = tid & 15;
    const int ty = tid >> 4;

    float row_minp[4], row_maxn[4];
    #pragma unroll
    for (int i = 0; i < 4; ++i) {
        row_minp[i] = minp[i0 + ty * 4 + i];
        row_maxn[i] = maxn[i0 + ty * 4 + i];
    }

    float ps[4] = {0.f, 0.f, 0.f, 0.f};
    float ns[4] = {0.f, 0.f, 0.f, 0.f};

    const float* ap = &As[(ty * 4) * LDW];
    const float* bp = &Bs[tx * LDW];

    for (int jt = 0; jt < jchunk; jt += TJ) {
        __syncthreads();
        for (int v = tid; v < TJ * (DDIM / 4); v += THREADS) {
            int c  = v >> 5;
            int k4 = (v & 31) << 2;
            *(float4*)&Bs[c * LDW + k4] =
                *(const float4*)&feats[(size_t)(j0 + jt + c) * DDIM + k4];
        }
        if (tid < TJ) Blab[tid] = labels[j0 + jt + tid];
        __syncthreads();

        float acc[4][4];
        #pragma unroll
        for (int i = 0; i < 4; ++i)
            #pragma unroll
            for (int j = 0; j < 4; ++j) acc[i][j] = 0.f;

        #pragma unroll 4
        for (int k = 0; k < DDIM; k += 4) {
            float4 a[4], b[4];
            #pragma unroll
            for (int i = 0; i < 4; ++i) a[i] = *(const float4*)&ap[i * LDW + k];
            #pragma unroll
            for (int j = 0; j < 4; ++j) b[j] = *(const float4*)&bp[(j * 16) * LDW + k];
            #pragma unroll
            for (int i = 0; i < 4; ++i)
                #pragma unroll
                for (int j = 0; j < 4; ++j) {
                    acc[i][j] = fmaf(a[i].x, b[j].x, acc[i][j]);
                    acc[i][j] = fmaf(a[i].y, b[j].y, acc[i][j]);
                    acc[i][j] = fmaf(a[i].z, b[j].z, acc[i][j]);
                    acc[i][j] = fmaf(a[i].w, b[j].w, acc[i][j]);
                }
        }

        #pragma unroll
        for (int i = 0; i < 4; ++i) {
            int la = Alab[ty * 4 + i];
            #pragma unroll
            for (int j = 0; j < 4; ++j) {
                int lb  = Blab[tx + j * 16];
                float s = acc[i][j];
                if (la == lb) {
                    if (s < 1.0f - F_EPS && (s - F_MARGIN < row_maxn[i]))
                        ps[i] += __expf(-F_SPOS * (s - F_THRESH));
                } else {
                    if (s + F_MARGIN > row_minp[i])
                        ns[i] += __expf(F_SNEG * (s - F_THRESH));
                }
            }
        }
    }

    #pragma unroll
    for (int off = 1; off < 16; off <<= 1) {
        #pragma unroll
        for (int i = 0; i < 4; ++i) {
            ps[i] += __shfl_xor(ps[i], off, 64);
            ns[i] += __shfl_xor(ns[i], off, 64);
        }
    }
    if (tx == 0) {
        #pragma unroll
        for (int i = 0; i < 4; ++i) {
            int row = i0 + ty * 4 + i;
            psum_part[(size_t)blockIdx.y * B + row] = ps[i];
            nsum_part[(size_t)blockIdx.y * B + row] = ns[i];
        }
    }
}

// ---------------------------------------------------------------- finalize
__global__ void ms_finalize(const float* __restrict__ psum_part,
                            const float* __restrict__ nsum_part,
                            const float* __restrict__ minp,
                            const float* __restrict__ maxn,
                            float* __restrict__ out, int B)
{
    int i = blockIdx.x * blockDim.x + threadIdx.x;
    float rl = 0.0f;
    if (i < B) {
        float ps = 0.f, ns = 0.f;
        #pragma unroll
        for (int s = 0; s < SPLITS; ++s) {
            ps += psum_part[(size_t)s * B + i];
            ns += nsum_part[(size_t)s * B + i];
        }
        bool has_pos = (minp[i] <  INFINITY);
        bool has_neg = (maxn[i] > -INFINITY);
        if (has_pos && has_neg && ps > 0.f && ns > 0.f)
            rl = log1pf(ps) / F_SPOS + log1pf(ns) / F_SNEG;
    }
    // block reduction (256 threads = 4 waves)
    #pragma unroll
    for (int off = 32; off > 0; off >>= 1) rl += __shfl_down(rl, off, 64);
    __shared__ float wsum[4];
    int lane = threadIdx.x & 63, w = threadIdx.x >> 6;
    if (lane == 0) wsum[w] = rl;
    __syncthreads();
    if (threadIdx.x == 0) {
        float t = wsum[0] + wsum[1] + wsum[2] + wsum[3];
        atomicAdd(out, t / (float)B);
    }
}

// ---------------------------------------------------------------- launch
extern "C" void kernel_launch(void* const* d_in, const int* in_sizes, int n_in,
                              void* d_out, int out_size, void* d_ws, size_t ws_size,
                              hipStream_t stream)
{
    const float* feats  = (const float*)d_in[0];
    const int*   labels = (const int*)d_in[1];
    const int B = in_sizes[1];          // 8192; D = in_sizes[0]/B = 128

    float* w = (float*)d_ws;
    float* minp_part = w;
    float* maxn_part = w + (size_t)SPLITS * B;
    float* psum_part = w + 2 * (size_t)SPLITS * B;
    float* nsum_part = w + 3 * (size_t)SPLITS * B;
    float* minp      = w + 4 * (size_t)SPLITS * B;
    float* maxn      = minp + B;

    hipMemsetAsync(d_out, 0, sizeof(float), stream);

    dim3 grid(B / TI, SPLITS);
    ms_stage1<<<grid, THREADS, 0, stream>>>(feats, labels, minp_part, maxn_part, B);
    ms_combine<<<(B + 255) / 256, 256, 0, stream>>>(minp_part, maxn_part, minp, maxn, B);
    ms_stage2<<<grid, THREADS, 0, stream>>>(feats, labels, minp, maxn,
                                            psum_part, nsum_part, B);
    ms_finalize<<<(B + 255) / 256, 256, 0, stream>>>(psum_part, nsum_part,
                                                     minp, maxn, (float*)d_out, B);
}

// Round 2
// 163.088 us; speedup vs baseline: 3.8608x; 3.8608x over previous
//
#include <hip/hip_runtime.h>
#include <hip/hip_bf16.h>
#include <math.h>

// MultiSimilarityLoss B=8192 D=128: sim = F·F^T via bf16 MFMA (16x16x32).
// Two passes: ms1 (row min_pos/max_neg), ms2 (masked exp sums, inline combine).
// Fragments load directly from global (2 MB bf16 feats is L1/L2-resident);
// no LDS / barriers in the MFMA hot loops.

#define B_N    8192
#define DDIM   128
#define JSPLIT 16
#define JRANGE (B_N / JSPLIT)   // 512 cols per block
#define JTILES (JRANGE / 32)    // 16 j-tiles of 32 cols

typedef __attribute__((ext_vector_type(8))) short bf16x8;  // 8 bf16 = 4 VGPRs
typedef __attribute__((ext_vector_type(4))) float f32x4;

static constexpr float ONE_EPS = 1.0f - 1e-5f;
static constexpr float F_MARGIN = 0.1f;
static constexpr float F_THRESH = 0.5f;

// ---------------------------------------------------------------- cast fp32 -> bf16 (RNE)
__global__ __launch_bounds__(256)
void ms_cast(const float* __restrict__ f, ushort* __restrict__ fb)
{
    int i = (blockIdx.x * 256 + threadIdx.x) * 4;
    float4 v = *(const float4*)(f + i);
    ushort4 o;
    uint u;
    u = __float_as_uint(v.x); o.x = (ushort)((u + 0x7fffu + ((u >> 16) & 1u)) >> 16);
    u = __float_as_uint(v.y); o.y = (ushort)((u + 0x7fffu + ((u >> 16) & 1u)) >> 16);
    u = __float_as_uint(v.z); o.z = (ushort)((u + 0x7fffu + ((u >> 16) & 1u)) >> 16);
    u = __float_as_uint(v.w); o.w = (ushort)((u + 0x7fffu + ((u >> 16) & 1u)) >> 16);
    *(ushort4*)(fb + i) = o;
}

// ---------------------------------------------------------------- stage 1: min_pos / max_neg
__global__ __launch_bounds__(256, 2)
void ms1(const ushort* __restrict__ fb, const int* __restrict__ labels,
         float* __restrict__ minp_part, float* __restrict__ maxn_part)
{
    const int tid  = threadIdx.x;
    const int w    = tid >> 6;          // wave 0..3 -> 64-row strip
    const int lane = tid & 63;
    const int q    = lane >> 4;         // quad 0..3
    const int c    = lane & 15;         // col within 16-tile
    const int i0   = blockIdx.x * 256;
    const int j0   = blockIdx.y * JRANGE;
    const int arow = i0 + w * 64;

    // A fragments: wave's 64 rows, full K=128, resident in VGPRs.
    bf16x8 afr[4][4];                   // [row-tile][k-step]
    int    la[4][4];                    // row labels per (row-tile, reg)
    #pragma unroll
    for (int rt = 0; rt < 4; ++rt) {
        #pragma unroll
        for (int ks = 0; ks < 4; ++ks)
            afr[rt][ks] = *(const bf16x8*)(fb + (size_t)(arow + rt * 16 + c) * DDIM + ks * 32 + q * 8);
        #pragma unroll
        for (int r = 0; r < 4; ++r)
            la[rt][r] = labels[arow + rt * 16 + q * 4 + r];
    }

    float vmin[4][4], vmax[4][4];
    #pragma unroll
    for (int rt = 0; rt < 4; ++rt)
        #pragma unroll
        for (int r = 0; r < 4; ++r) { vmin[rt][r] = INFINITY; vmax[rt][r] = -INFINITY; }

    for (int jt = 0; jt < JTILES; ++jt) {
        const int jb = j0 + jt * 32;
        bf16x8 bfr[2][4];               // [col-tile][k-step] — identical across block's 4 waves (L1 reuse)
        #pragma unroll
        for (int ct = 0; ct < 2; ++ct)
            #pragma unroll
            for (int ks = 0; ks < 4; ++ks)
                bfr[ct][ks] = *(const bf16x8*)(fb + (size_t)(jb + ct * 16 + c) * DDIM + ks * 32 + q * 8);
        int lbv[2] = { labels[jb + c], labels[jb + 16 + c] };

        #pragma unroll
        for (int rt = 0; rt < 4; ++rt) {
            #pragma unroll
            for (int ct = 0; ct < 2; ++ct) {
                f32x4 acc = {0.f, 0.f, 0.f, 0.f};
                #pragma unroll
                for (int ks = 0; ks < 4; ++ks)
                    acc = __builtin_amdgcn_mfma_f32_16x16x32_bf16(afr[rt][ks], bfr[ct][ks], acc, 0, 0, 0);
                int lb = lbv[ct];
                #pragma unroll
                for (int r = 0; r < 4; ++r) {
                    float s = acc[r];
                    bool same = (la[rt][r] == lb);
                    float cm = (same && s < ONE_EPS) ? s : INFINITY;   // pos candidate
                    float cx = same ? -INFINITY : s;                    // neg candidate
                    vmin[rt][r] = fminf(vmin[rt][r], cm);
                    vmax[rt][r] = fmaxf(vmax[rt][r], cx);
                }
            }
        }
    }

    // reduce across the 16 columns held by lanes c=0..15 of each quad
    #pragma unroll
    for (int off = 1; off < 16; off <<= 1) {
        #pragma unroll
        for (int rt = 0; rt < 4; ++rt)
            #pragma unroll
            for (int r = 0; r < 4; ++r) {
                vmin[rt][r] = fminf(vmin[rt][r], __shfl_xor(vmin[rt][r], off, 64));
                vmax[rt][r] = fmaxf(vmax[rt][r], __shfl_xor(vmax[rt][r], off, 64));
            }
    }
    if (c == 0) {
        #pragma unroll
        for (int rt = 0; rt < 4; ++rt)
            #pragma unroll
            for (int r = 0; r < 4; ++r) {
                int row = arow + rt * 16 + q * 4 + r;
                minp_part[(size_t)blockIdx.y * B_N + row] = vmin[rt][r];
                maxn_part[(size_t)blockIdx.y * B_N + row] = vmax[rt][r];
            }
    }
}

// ---------------------------------------------------------------- stage 2: masked exp sums
__global__ __launch_bounds__(256, 2)
void ms2(const ushort* __restrict__ fb, const int* __restrict__ labels,
         const float* __restrict__ minp_part, const float* __restrict__ maxn_part,
         float* __restrict__ minpc, float* __restrict__ maxnc,
         float* __restrict__ psum_part, float* __restrict__ nsum_part)
{
    const int tid  = threadIdx.x;
    const int w    = tid >> 6;
    const int lane = tid & 63;
    const int q    = lane >> 4;
    const int c    = lane & 15;
    const int i0   = blockIdx.x * 256;
    const int j0   = blockIdx.y * JRANGE;
    const int arow = i0 + w * 64;

    // inline combine of stage-1 partials for this block's 256 rows
    __shared__ float smn[256], smx[256];
    {
        int row = i0 + tid;
        float mn = INFINITY, mx = -INFINITY;
        #pragma unroll
        for (int s = 0; s < JSPLIT; ++s) {
            mn = fminf(mn, minp_part[(size_t)s * B_N + row]);
            mx = fmaxf(mx, maxn_part[(size_t)s * B_N + row]);
        }
        smn[tid] = mn; smx[tid] = mx;
        if (blockIdx.y == 0) { minpc[row] = mn; maxnc[row] = mx; }  // for finalize
    }
    __syncthreads();

    bf16x8 afr[4][4];
    int    la[4][4];
    float  rmn[4][4], rmx[4][4];
    #pragma unroll
    for (int rt = 0; rt < 4; ++rt) {
        #pragma unroll
        for (int ks = 0; ks < 4; ++ks)
            afr[rt][ks] = *(const bf16x8*)(fb + (size_t)(arow + rt * 16 + c) * DDIM + ks * 32 + q * 8);
        #pragma unroll
        for (int r = 0; r < 4; ++r) {
            int lrow = w * 64 + rt * 16 + q * 4 + r;
            la[rt][r]  = labels[i0 + lrow];
            rmn[rt][r] = smn[lrow];
            rmx[rt][r] = smx[lrow];
        }
    }

    float ps[4][4], ns[4][4];
    #pragma unroll
    for (int rt = 0; rt < 4; ++rt)
        #pragma unroll
        for (int r = 0; r < 4; ++r) { ps[rt][r] = 0.f; ns[rt][r] = 0.f; }

    for (int jt = 0; jt < JTILES; ++jt) {
        const int jb = j0 + jt * 32;
        bf16x8 bfr[2][4];
        #pragma unroll
        for (int ct = 0; ct < 2; ++ct)
            #pragma unroll
            for (int ks = 0; ks < 4; ++ks)
                bfr[ct][ks] = *(const bf16x8*)(fb + (size_t)(jb + ct * 16 + c) * DDIM + ks * 32 + q * 8);
        int lbv[2] = { labels[jb + c], labels[jb + 16 + c] };

        #pragma unroll
        for (int rt = 0; rt < 4; ++rt) {
            #pragma unroll
            for (int ct = 0; ct < 2; ++ct) {
                f32x4 acc = {0.f, 0.f, 0.f, 0.f};
                #pragma unroll
                for (int ks = 0; ks < 4; ++ks)
                    acc = __builtin_amdgcn_mfma_f32_16x16x32_bf16(afr[rt][ks], bfr[ct][ks], acc, 0, 0, 0);
                int lb = lbv[ct];
                #pragma unroll
                for (int r = 0; r < 4; ++r) {
                    float s = acc[r];
                    bool same = (la[rt][r] == lb);
                    float k = same ? -2.0f : 40.0f;
                    float e = __expf(k * (s - F_THRESH));     // one exp per element
                    bool pok = same && (s < ONE_EPS) && (s - F_MARGIN < rmx[rt][r]);
                    bool nok = (!same) && (s + F_MARGIN > rmn[rt][r]);
                    ps[rt][r] += pok ? e : 0.0f;
                    ns[rt][r] += nok ? e : 0.0f;
                }
            }
        }
    }

    #pragma unroll
    for (int off = 1; off < 16; off <<= 1) {
        #pragma unroll
        for (int rt = 0; rt < 4; ++rt)
            #pragma unroll
            for (int r = 0; r < 4; ++r) {
                ps[rt][r] += __shfl_xor(ps[rt][r], off, 64);
                ns[rt][r] += __shfl_xor(ns[rt][r], off, 64);
            }
    }
    if (c == 0) {
        #pragma unroll
        for (int rt = 0; rt < 4; ++rt)
            #pragma unroll
            for (int r = 0; r < 4; ++r) {
                int row = arow + rt * 16 + q * 4 + r;
                psum_part[(size_t)blockIdx.y * B_N + row] = ps[rt][r];
                nsum_part[(size_t)blockIdx.y * B_N + row] = ns[rt][r];
            }
    }
}

// ---------------------------------------------------------------- finalize
__global__ __launch_bounds__(256)
void ms_fin(const float* __restrict__ psum_part, const float* __restrict__ nsum_part,
            const float* __restrict__ minpc, const float* __restrict__ maxnc,
            float* __restrict__ out)
{
    int i = blockIdx.x * 256 + threadIdx.x;
    float ps = 0.f, ns = 0.f;
    #pragma unroll
    for (int s = 0; s < JSPLIT; ++s) {
        ps += psum_part[(size_t)s * B_N + i];
        ns += nsum_part[(size_t)s * B_N + i];
    }
    float rl = 0.f;
    if (minpc[i] < INFINITY && maxnc[i] > -INFINITY && ps > 0.f && ns > 0.f)
        rl = log1pf(ps) * 0.5f + log1pf(ns) * 0.025f;   // /SCALE_POS, /SCALE_NEG

    #pragma unroll
    for (int off = 32; off > 0; off >>= 1) rl += __shfl_down(rl, off, 64);
    __shared__ float wsum[4];
    int lane = threadIdx.x & 63, wv = threadIdx.x >> 6;
    if (lane == 0) wsum[wv] = rl;
    __syncthreads();
    if (threadIdx.x == 0)
        atomicAdd(out, (wsum[0] + wsum[1] + wsum[2] + wsum[3]) * (1.0f / (float)B_N));
}

// ---------------------------------------------------------------- launch
extern "C" void kernel_launch(void* const* d_in, const int* in_sizes, int n_in,
                              void* d_out, int out_size, void* d_ws, size_t ws_size,
                              hipStream_t stream)
{
    const float* feats  = (const float*)d_in[0];
    const int*   labels = (const int*)d_in[1];

    char*   wsb       = (char*)d_ws;
    ushort* fb        = (ushort*)wsb;                          // 8192*128 bf16 = 2 MB
    float*  minp_part = (float*)(wsb + (size_t)2 * 1024 * 1024);
    float*  maxn_part = minp_part + (size_t)JSPLIT * B_N;
    float*  psum_part = maxn_part + (size_t)JSPLIT * B_N;
    float*  nsum_part = psum_part + (size_t)JSPLIT * B_N;
    float*  minpc     = nsum_part + (size_t)JSPLIT * B_N;
    float*  maxnc     = minpc + B_N;

    hipMemsetAsync(d_out, 0, sizeof(float), stream);

    ms_cast<<<(B_N * DDIM) / (256 * 4), 256, 0, stream>>>(feats, fb);
    ms1<<<dim3(B_N / 256, JSPLIT), 256, 0, stream>>>(fb, labels, minp_part, maxn_part);
    ms2<<<dim3(B_N / 256, JSPLIT), 256, 0, stream>>>(fb, labels, minp_part, maxn_part,
                                                     minpc, maxnc, psum_part, nsum_part);
    ms_fin<<<B_N / 256, 256, 0, stream>>>(psum_part, nsum_part, minpc, maxnc, (float*)d_out);
}